// Round 7
// baseline (232.603 us; speedup 1.0000x reference)
//
#include <hip/hip_runtime.h>
#include <hip/hip_bf16.h>

#define NB 32
#define NA 1024
#define ND 128
#define TG 16
#define KNB 16   // stored earlier-neighbor cap; overflow -> rescan fallback

__device__ __forceinline__ float gelu_exact(float x) {
    return 0.5f * x * (1.0f + erff(x * 0.7071067811865476f));
}

// exact mul+add (no fma contraction) to match the np reference bit-for-bit
__device__ __forceinline__ float dist2(float ax, float ay, float bx, float by) {
    float dx = ax - bx, dy = ay - by;
    return __fadd_rn(__fmul_rn(dx, dx), __fmul_rn(dy, dy));
}

// ---------------------------------------------------------------------------
// Clustering as a parallel fixed point (lex-first MIS of the proximity graph):
//   leader  <=> valid, all earlier valid nbrs (d<thr) absorbed
//   absorbed<=> some earlier valid nbr is a leader
// Monotone rounds (status 0->1/2 only) are race-safe; min undecided index
// always resolves, so convergence is guaranteed; random data: ~10-20 rounds.
// Group of absorbed q = min-index leader nbr; gid = leader rank by index.
// One block of 1024 threads per batch, 1 thread per point. Block NB computes
// the MLP(0) row used by the mlp fast path.
// ---------------------------------------------------------------------------
__global__ __launch_bounds__(1024, 1) void fused_kernel(
    const float2* __restrict__ coords, const int* __restrict__ mask,
    int* __restrict__ gcount, int* __restrict__ memb_ws,
    int* __restrict__ goff_ws, float* __restrict__ gcntf_ws,
    float* __restrict__ out_mask, float* __restrict__ out_a2g,
    const float* __restrict__ b1, const float* __restrict__ W2,
    const float* __restrict__ b2, float* __restrict__ empty_row)
{
    __shared__ __align__(16) float2 xy[NA];   // 8 KB (sentinel for invalid)
    __shared__ int   stat[NA];                // 4 KB; later reused as gid table
    __shared__ short nbr[NA * KNB];           // 32 KB
    __shared__ int   bufA[NA];                // 4 KB
    __shared__ int   bufB[NA];                // 4 KB
    __shared__ int   membs[NA];               // 4 KB
    __shared__ int   cnts[NA];                // 4 KB
    __shared__ int   undec_cnt;

    const int tid = threadIdx.x;

    if (blockIdx.x == NB) {
        // empty row = gelu(b1) @ W2 + b2 (generic in b1/b2)
        float* hbuf = (float*)xy;
        if (tid < ND) hbuf[tid] = gelu_exact(b1[tid]);
        __syncthreads();
        if (tid < ND) {
            float acc = b2[tid];
            for (int k = 0; k < ND; ++k) acc += hbuf[k] * W2[k * ND + tid];
            empty_row[tid] = acc;
        }
        return;
    }

    const int b = blockIdx.x;
    const float2 praw = coords[(b << 10) + tid];
    const bool valid = mask[(b << 10) + tid] != 0;
    // sentinel: invalid points never within thr of anything real
    const float2 p = valid ? praw : make_float2(1e30f, 1e30f);
    xy[tid] = p;
    int st = valid ? 0 : 2;       // 0 undecided, 1 leader, 2 absorbed/invalid
    stat[tid] = st;
    if (tid == 0) undec_cnt = 0;
    __syncthreads();

    const float thr2 = 0.05f * 0.05f;

    // ---- build earlier-neighbor list (parallel, vectorized LDS reads) ----
    int nst = 0;
    bool heavy = false;
    {
        const float4* xy4 = (const float4*)xy;
        const int np2 = tid >> 1;
        for (int j2 = 0; j2 < np2; ++j2) {
            float4 two = xy4[j2];
            const int j0 = j2 * 2;
            float da = dist2(p.x, p.y, two.x, two.y);
            float db = dist2(p.x, p.y, two.z, two.w);
            if (da < thr2) { if (nst < KNB) nbr[tid * KNB + nst++] = (short)j0; else heavy = true; }
            if (db < thr2) { if (nst < KNB) nbr[tid * KNB + nst++] = (short)(j0 + 1); else heavy = true; }
        }
        if (tid & 1) {
            float2 q = xy[tid - 1];
            float dc = dist2(p.x, p.y, q.x, q.y);
            if (dc < thr2) { if (nst < KNB) nbr[tid * KNB + nst++] = (short)(tid - 1); else heavy = true; }
        }
    }
    __syncthreads();

    // ---- monotone decision rounds ----
    for (int round = 0; round < 4096; ++round) {
        if (st == 0) {
            bool anyL = false, anyU = false;
            if (!heavy) {
                for (int k = 0; k < nst; ++k) {
                    int s = stat[(int)nbr[tid * KNB + k]];
                    anyL |= (s == 1);
                    anyU |= (s == 0);
                }
            } else {
                for (int j = 0; j < tid; ++j) {
                    float2 q = xy[j];
                    if (dist2(p.x, p.y, q.x, q.y) < thr2) {
                        int s = stat[j];
                        anyL |= (s == 1);
                        anyU |= (s == 0);
                    }
                }
            }
            if (anyL)       { st = 2; stat[tid] = 2; }
            else if (!anyU) { st = 1; stat[tid] = 1; }
        }
        __syncthreads();
        unsigned long long um = __ballot(st == 0);
        if ((tid & 63) == 0 && um != 0ULL)
            atomicAdd(&undec_cnt, (int)__popcll(um));
        __syncthreads();
        const int u = undec_cnt;
        __syncthreads();
        if (tid == 0) undec_cnt = 0;
        if (u == 0) break;
    }

    // ---- resolve absorbed -> min-index leader nbr (lists are ascending) ----
    int leader = -1;
    if (st == 2 && valid) {
        if (!heavy) {
            for (int k = 0; k < nst; ++k) {
                int j = (int)nbr[tid * KNB + k];
                if (stat[j] == 1) { leader = j; break; }
            }
        } else {
            for (int j = 0; j < tid; ++j) {
                float2 q = xy[j];
                if (dist2(p.x, p.y, q.x, q.y) < thr2 && stat[j] == 1) { leader = j; break; }
            }
        }
    }

    // ---- gid = rank of leader by index (Hillis-Steele scan, 10 steps) ----
    bufA[tid] = (st == 1) ? 1 : 0;
    __syncthreads();
    {
        int* src = bufA; int* dst = bufB;
        for (int d = 1; d < NA; d <<= 1) {
            int v = src[tid];
            if (tid >= d) v += src[tid - d];
            dst[tid] = v;
            __syncthreads();
            int* t = src; src = dst; dst = t;
        }   // even #steps -> result in bufA
    }
    const int G = bufA[NA - 1];
    const int mygid = bufA[tid] - ((st == 1) ? 1 : 0);
    stat[tid] = mygid;          // reuse stat as gid table
    __syncthreads();

    int asg;
    if (!valid) asg = -2;
    else if (st == 1) asg = mygid;
    else asg = (leader >= 0) ? stat[leader] : 0;

    // ---- CSR: counts, offsets, member scatter ----
    cnts[tid] = 0;
    membs[tid] = 0;
    __syncthreads();
    if (asg >= 0) atomicAdd(&cnts[asg], 1);
    __syncthreads();
    bufA[tid] = cnts[tid];
    __syncthreads();
    {
        int* src = bufA; int* dst = bufB;
        for (int d = 1; d < NA; d <<= 1) {
            int v = src[tid];
            if (tid >= d) v += src[tid - d];
            dst[tid] = v;
            __syncthreads();
            int* t = src; src = dst; dst = t;
        }
    }
    const int excl = bufA[tid] - cnts[tid];
    goff_ws[(b << 10) + tid]  = excl;
    gcntf_ws[(b << 10) + tid] = (float)cnts[tid];
    bufB[tid] = excl;
    __syncthreads();
    if (asg >= 0) {
        int pos = atomicAdd(&bufB[asg], 1);
        membs[pos] = tid;
    }
    __syncthreads();

    memb_ws[(b << 10) + tid] = membs[tid];
    out_a2g[(b << 10) + tid] = (asg == -2) ? -1.0f : (float)asg;
    out_mask[(b << 10) + tid] = (tid < G) ? 1.0f : 0.0f;
    if (tid == 0) gcount[b] = G;
}

// ---------------------------------------------------------------------------
// Token gather (16 thr/group, coalesced) + 2-layer MLP, W read from L2
// (every heavy block reads the same 128 KB -> broadcast; no LDS W staging).
// ---------------------------------------------------------------------------
__global__ __launch_bounds__(256) void mlp_kernel(
    const float* __restrict__ emb, const int* __restrict__ memb,
    const int* __restrict__ goff, const float* __restrict__ gcntf,
    const int* __restrict__ gcount, const float* __restrict__ empty_row,
    const float4* __restrict__ W1, const float* __restrict__ b1,
    const float4* __restrict__ W2, const float* __restrict__ b2,
    float* __restrict__ out0)
{
    const int b = blockIdx.y;
    const int g0 = blockIdx.x * TG;
    const int tid = threadIdx.x;
    float* ob = out0 + ((size_t)(b << 10) + g0) * ND;

    if (g0 >= gcount[b]) {
        float4 r = ((const float4*)empty_row)[tid & 31];
        float4* ob4 = (float4*)ob;
        ob4[tid] = r;
        ob4[tid + 256] = r;
        return;
    }

    __shared__ float tok[TG][ND];   // 8 KB: tokens, then h

    {   // gather means: group gl served by 16 threads (sub), 32B each
        const int gl = tid >> 4;
        const int sub = tid & 15;
        const int gi = (b << 10) + g0 + gl;
        const int n = (int)gcntf[gi];          // 0 for g >= G -> zero token
        const int off = goff[gi];
        const int* mb = memb + (b << 10) + off;
        float a0=0,a1=0,a2=0,a3=0,a4=0,a5=0,a6=0,a7=0;
        for (int k = 0; k < n; ++k) {
            const int a = mb[k];
            const float4* e4 = (const float4*)(emb + ((size_t)(b << 10) + a) * ND + sub * 8);
            float4 v0 = e4[0], v1 = e4[1];
            a0 += v0.x; a1 += v0.y; a2 += v0.z; a3 += v0.w;
            a4 += v1.x; a5 += v1.y; a6 += v1.z; a7 += v1.w;
        }
        const float den = fmaxf((float)n, 1.0f);
        *(float4*)&tok[gl][sub * 8]     = make_float4(a0/den, a1/den, a2/den, a3/den);
        *(float4*)&tok[gl][sub * 8 + 4] = make_float4(a4/den, a5/den, a6/den, a7/den);
    }
    __syncthreads();

    const int jq = tid & 31;   // output quad j = jq*4
    const int gs = tid >> 5;   // token rows gs, gs+8
    float acc[2][4];
#pragma unroll
    for (int jj = 0; jj < 4; ++jj) { acc[0][jj] = 0.0f; acc[1][jj] = 0.0f; }

#pragma unroll 4
    for (int dd = 0; dd < ND; ++dd) {
        float4 wv = W1[dd * 32 + jq];          // L2 broadcast
        float t0 = tok[gs][dd];                // LDS broadcast
        float t1 = tok[gs + 8][dd];
        acc[0][0] += t0 * wv.x; acc[0][1] += t0 * wv.y;
        acc[0][2] += t0 * wv.z; acc[0][3] += t0 * wv.w;
        acc[1][0] += t1 * wv.x; acc[1][1] += t1 * wv.y;
        acc[1][2] += t1 * wv.z; acc[1][3] += t1 * wv.w;
    }
    float4 bb = ((const float4*)b1)[jq];
    __syncthreads();   // all layer-1 tok reads done before overwrite
    {
        float4 h;
        h.x = gelu_exact(acc[0][0] + bb.x);
        h.y = gelu_exact(acc[0][1] + bb.y);
        h.z = gelu_exact(acc[0][2] + bb.z);
        h.w = gelu_exact(acc[0][3] + bb.w);
        *(float4*)&tok[gs][jq * 4] = h;
        h.x = gelu_exact(acc[1][0] + bb.x);
        h.y = gelu_exact(acc[1][1] + bb.y);
        h.z = gelu_exact(acc[1][2] + bb.z);
        h.w = gelu_exact(acc[1][3] + bb.w);
        *(float4*)&tok[gs + 8][jq * 4] = h;
    }
    __syncthreads();

#pragma unroll
    for (int jj = 0; jj < 4; ++jj) { acc[0][jj] = 0.0f; acc[1][jj] = 0.0f; }
#pragma unroll 4
    for (int dd = 0; dd < ND; ++dd) {
        float4 wv = W2[dd * 32 + jq];
        float t0 = tok[gs][dd];
        float t1 = tok[gs + 8][dd];
        acc[0][0] += t0 * wv.x; acc[0][1] += t0 * wv.y;
        acc[0][2] += t0 * wv.z; acc[0][3] += t0 * wv.w;
        acc[1][0] += t1 * wv.x; acc[1][1] += t1 * wv.y;
        acc[1][2] += t1 * wv.z; acc[1][3] += t1 * wv.w;
    }
    float4 cbv = ((const float4*)b2)[jq];
    {
        float4 o;
        o.x = acc[0][0] + cbv.x; o.y = acc[0][1] + cbv.y;
        o.z = acc[0][2] + cbv.z; o.w = acc[0][3] + cbv.w;
        *(float4*)&ob[(size_t)gs * ND + jq * 4] = o;
        o.x = acc[1][0] + cbv.x; o.y = acc[1][1] + cbv.y;
        o.z = acc[1][2] + cbv.z; o.w = acc[1][3] + cbv.w;
        *(float4*)&ob[(size_t)(gs + 8) * ND + jq * 4] = o;
    }
}

extern "C" void kernel_launch(void* const* d_in, const int* in_sizes, int n_in,
                              void* d_out, int out_size, void* d_ws, size_t ws_size,
                              hipStream_t stream) {
    const float* emb    = (const float*)d_in[0];   // [B,A,D]
    const float* coords = (const float*)d_in[1];   // [B,A,2]
    const int*   mask   = (const int*)d_in[2];     // [B,A]
    const float* W1     = (const float*)d_in[3];   // [D,D]
    const float* b1     = (const float*)d_in[4];   // [D]
    const float* W2     = (const float*)d_in[5];   // [D,D]
    const float* b2     = (const float*)d_in[6];   // [D]

    float* out0 = (float*)d_out;                    // [B,A,D]
    float* out1 = out0 + (size_t)NB * NA * ND;      // group_mask
    float* out2 = out1 + (size_t)NB * NA;           // agent_to_group

    // workspace: CSR + gcount + empty_row
    int*   ws_memb  = (int*)d_ws;                         // B*A
    int*   ws_goff  = ws_memb + (size_t)NB * NA;          // B*A
    float* ws_gcntf = (float*)(ws_goff + (size_t)NB * NA);// B*A
    int*   ws_gcnt  = (int*)(ws_gcntf + (size_t)NB * NA); // B
    float* ws_empty = (float*)(ws_gcnt + NB);             // D

    fused_kernel<<<NB + 1, 1024, 0, stream>>>(
        (const float2*)coords, mask,
        ws_gcnt, ws_memb, ws_goff, ws_gcntf,
        out1, out2, b1, W2, b2, ws_empty);
    mlp_kernel<<<dim3(NA / TG, NB), 256, 0, stream>>>(
        emb, ws_memb, ws_goff, ws_gcntf, ws_gcnt, ws_empty,
        (const float4*)W1, b1, (const float4*)W2, b2, out0);
}

// Round 8
// 154.585 us; speedup vs baseline: 1.5047x; 1.5047x over previous
//
#include <hip/hip_runtime.h>
#include <hip/hip_bf16.h>

#define NB 32
#define NA 1024
#define ND 128
#define TG 16

__device__ __forceinline__ float gelu_exact(float x) {
    return 0.5f * x * (1.0f + erff(x * 0.7071067811865476f));
}

// exact mul+add (no fma contraction) to match the np reference bit-for-bit
__device__ __forceinline__ float dist2(float ax, float ay, float bx, float by) {
    float dx = ax - bx, dy = ay - by;
    return __fadd_rn(__fmul_rn(dx, dx), __fmul_rn(dy, dy));
}

// ---------------------------------------------------------------------------
// Fused clustering + CSR + token means. One block of 1024 threads per batch.
// Point i -> wave i/64, lane i%64. Greedy absorption only affects
// later-indexed points, so wave w produces its leaders after waves <w finish,
// while waves >w consume the leader stream concurrently from an LDS ring.
// Producer publishes lead_cnt every 8 leaders (release); per-leader stores
// are plain ds_writes, keeping the serial chain free of lgkmcnt drains.
// Consumers hard-block only on done_s[w-1] (release-stored after the final
// publish), so batched publication is safe (acquire/release pairing).
// Block NB computes the MLP(0) row used by the mlp fast path.
// ---------------------------------------------------------------------------
__global__ __launch_bounds__(1024, 1) void fused_kernel(
    const float2* __restrict__ coords, const int* __restrict__ mask,
    const float* __restrict__ emb,
    int* __restrict__ gcount, float* __restrict__ tokens,
    float* __restrict__ out_mask, float* __restrict__ out_a2g,
    const float* __restrict__ b1, const float* __restrict__ W2,
    const float* __restrict__ b2, float* __restrict__ empty_row)
{
    __shared__ float2 ring[NA];     // leader coords, gid = ring index
    __shared__ int cnt_s[NA];
    __shared__ int bufA[NA];
    __shared__ int bufB[NA];
    __shared__ int memb[NA];
    __shared__ int done_s[16];
    __shared__ int lead_cnt;

    const int tid = threadIdx.x;

    if (blockIdx.x == NB) {
        // empty row = gelu(b1) @ W2 + b2 (runs concurrently with clustering)
        float* hbuf = (float*)ring;
        if (tid < ND) hbuf[tid] = gelu_exact(b1[tid]);
        __syncthreads();
        if (tid < ND) {
            float acc = b2[tid];
            for (int k = 0; k < ND; ++k) acc += hbuf[k] * W2[k * ND + tid];
            empty_row[tid] = acc;
        }
        return;
    }

    const int b = blockIdx.x;
    const int w = tid >> 6;
    const int lane = tid & 63;

    if (tid < 16) done_s[tid] = -1;
    if (tid == 0) lead_cnt = 0;

    float2 p = coords[(b << 10) + tid];
    const bool valid = mask[(b << 10) + tid] != 0;
    int asg = valid ? -1 : -2;
    bool alive = valid;
    const float thr2 = 0.05f * 0.05f;

    __syncthreads();

    int seen = 0;
    int target = (w == 0) ? 0 : -1;

    // -------- consume earlier waves' leaders as they are published --------
    while (true) {
        int c = __hip_atomic_load(&lead_cnt, __ATOMIC_ACQUIRE,
                                  __HIP_MEMORY_SCOPE_WORKGROUP);
        if (c > seen) {
            do {
                float2 l = ring[seen];
                float d2 = dist2(p.x, p.y, l.x, l.y);
                if (alive && d2 < thr2) { asg = seen; alive = false; }
                ++seen;
            } while (seen < c);
            continue;
        }
        if (target < 0)
            target = __hip_atomic_load(&done_s[w - 1], __ATOMIC_ACQUIRE,
                                       __HIP_MEMORY_SCOPE_WORKGROUP);
        if (target >= 0 && seen >= target) break;
        __builtin_amdgcn_s_sleep(1);
    }

    // -------- produce this wave's leaders (batched publication) --------
    __builtin_amdgcn_s_setprio(1);
    int pend = 0;
    unsigned long long bal;
    while ((bal = __ballot(alive)) != 0ULL) {
        const int L = (int)__builtin_ctzll(bal);         // wave-uniform
        const float lx = __builtin_bit_cast(float,
            __builtin_amdgcn_readlane(__builtin_bit_cast(int, p.x), L));
        const float ly = __builtin_bit_cast(float,
            __builtin_amdgcn_readlane(__builtin_bit_cast(int, p.y), L));
        float d2 = dist2(p.x, p.y, lx, ly);
        bool take = alive && (d2 < thr2);                // lane L: d2==0 -> take
        if (take) { asg = seen; alive = false; }
        if (lane == 0) ring[seen] = make_float2(lx, ly); // plain ds_write
        ++seen;
        if (++pend == 8) {                                // publish every 8
            if (lane == 0)
                __hip_atomic_store(&lead_cnt, seen, __ATOMIC_RELEASE,
                                   __HIP_MEMORY_SCOPE_WORKGROUP);
            pend = 0;
        }
    }
    if (lane == 0) {
        __hip_atomic_store(&lead_cnt, seen, __ATOMIC_RELEASE,
                           __HIP_MEMORY_SCOPE_WORKGROUP);
        __hip_atomic_store(&done_s[w], seen, __ATOMIC_RELEASE,
                           __HIP_MEMORY_SCOPE_WORKGROUP);
    }
    __builtin_amdgcn_s_setprio(0);

    __syncthreads();
    const int G = lead_cnt;

    // -------- phase 2: CSR (counts, scan, scatter) --------
    cnt_s[tid] = 0;
    __syncthreads();
    if (asg >= 0) atomicAdd(&cnt_s[asg], 1);
    __syncthreads();

    bufA[tid] = cnt_s[tid];
    __syncthreads();
    int* src = bufA;
    int* dst = bufB;
    for (int d = 1; d < NA; d <<= 1) {      // 10 steps -> ends with src == bufA
        int v = src[tid];
        if (tid >= d) v += src[tid - d];
        dst[tid] = v;
        __syncthreads();
        int* tswap = src; src = dst; dst = tswap;
    }
    const int excl = src[tid] - cnt_s[tid];
    bufB[tid] = excl;    // group offsets (persist)
    bufA[tid] = excl;    // scatter cursor
    __syncthreads();
    if (asg >= 0) {
        int ppos = atomicAdd(&bufA[asg], 1);
        memb[ppos] = tid;
    }
    __syncthreads();

    // -------- per-agent outputs --------
    out_a2g[(b << 10) + tid] = (asg == -2) ? -1.0f : (float)asg;
    out_mask[(b << 10) + tid] = (tid < G) ? 1.0f : 0.0f;
    if (tid == 0) gcount[b] = G;

    // -------- token means (wave w: groups w, w+16, ...) --------
    const int Gpad = (G + TG - 1) & ~(TG - 1);
    const float* eb = emb + ((size_t)(b) << 10) * ND;
    float* tb = tokens + ((size_t)(b) << 10) * ND;
    for (int g = w; g < Gpad; g += 16) {
        float a0 = 0.0f, a1 = 0.0f;
        if (g < G) {
            const int n = cnt_s[g];
            const int off = bufB[g];
            for (int k = 0; k < n; ++k) {
                const int a = memb[off + k];
                const float* ea = eb + (size_t)a * ND;
                a0 += ea[lane];          // coalesced 256B per member
                a1 += ea[lane + 64];
            }
            const float den = fmaxf((float)n, 1.0f);
            a0 /= den; a1 /= den;
        }
        tb[(size_t)g * ND + lane] = a0;       // zero rows for g in [G, Gpad)
        tb[(size_t)g * ND + lane + 64] = a1;  // -> mlp computes MLP(0) there
    }
}

// ---------------- 2-layer MLP, TG=16 tokens per block (R6 version) -----------
__global__ __launch_bounds__(256, 2) void mlp_kernel(
    const float* __restrict__ tokens, const int* __restrict__ gcount,
    const float* __restrict__ empty_row,
    const float4* __restrict__ W1, const float* __restrict__ b1,
    const float4* __restrict__ W2, const float* __restrict__ b2,
    float* __restrict__ out0)
{
    const int b = blockIdx.y;
    const int g0 = blockIdx.x * TG;
    const int tid = threadIdx.x;
    float* ob = out0 + ((size_t)(b << 10) + g0) * ND;

    if (g0 >= gcount[b]) {
        float4 r = ((const float4*)empty_row)[tid & 31];
        float4* ob4 = (float4*)ob;
        ob4[tid] = r;
        ob4[tid + 256] = r;
        return;
    }

    __shared__ float4 Wl[4096];      // 64 KB
    __shared__ float tok[TG][ND];    // 8 KB: tokens, then h

    {
        const float4* tsrc = (const float4*)(tokens + ((size_t)(b << 10) + g0) * ND);
        float4* tdst = (float4*)&tok[0][0];
        tdst[tid] = tsrc[tid];
        tdst[tid + 256] = tsrc[tid + 256];
    }
#pragma unroll
    for (int i = 0; i < 16; ++i) Wl[tid + i * 256] = W1[tid + i * 256];
    __syncthreads();

    const int jq = tid & 31;
    const int gs = tid >> 5;
    float acc[2][4];
#pragma unroll
    for (int jj = 0; jj < 4; ++jj) { acc[0][jj] = 0.0f; acc[1][jj] = 0.0f; }

#pragma unroll 4
    for (int dd = 0; dd < ND; ++dd) {
        float4 wv = Wl[dd * 32 + jq];
        float t0 = tok[gs][dd];
        float t1 = tok[gs + 8][dd];
        acc[0][0] += t0 * wv.x; acc[0][1] += t0 * wv.y;
        acc[0][2] += t0 * wv.z; acc[0][3] += t0 * wv.w;
        acc[1][0] += t1 * wv.x; acc[1][1] += t1 * wv.y;
        acc[1][2] += t1 * wv.z; acc[1][3] += t1 * wv.w;
    }
    float4 bb = ((const float4*)b1)[jq];
    __syncthreads();   // all layer-1 tok reads done before overwrite
    {
        float4 h;
        h.x = gelu_exact(acc[0][0] + bb.x);
        h.y = gelu_exact(acc[0][1] + bb.y);
        h.z = gelu_exact(acc[0][2] + bb.z);
        h.w = gelu_exact(acc[0][3] + bb.w);
        *(float4*)&tok[gs][jq * 4] = h;
        h.x = gelu_exact(acc[1][0] + bb.x);
        h.y = gelu_exact(acc[1][1] + bb.y);
        h.z = gelu_exact(acc[1][2] + bb.z);
        h.w = gelu_exact(acc[1][3] + bb.w);
        *(float4*)&tok[gs + 8][jq * 4] = h;
    }
#pragma unroll
    for (int i = 0; i < 16; ++i) Wl[tid + i * 256] = W2[tid + i * 256];
    __syncthreads();

#pragma unroll
    for (int jj = 0; jj < 4; ++jj) { acc[0][jj] = 0.0f; acc[1][jj] = 0.0f; }
#pragma unroll 4
    for (int dd = 0; dd < ND; ++dd) {
        float4 wv = Wl[dd * 32 + jq];
        float t0 = tok[gs][dd];
        float t1 = tok[gs + 8][dd];
        acc[0][0] += t0 * wv.x; acc[0][1] += t0 * wv.y;
        acc[0][2] += t0 * wv.z; acc[0][3] += t0 * wv.w;
        acc[1][0] += t1 * wv.x; acc[1][1] += t1 * wv.y;
        acc[1][2] += t1 * wv.z; acc[1][3] += t1 * wv.w;
    }
    float4 cbv = ((const float4*)b2)[jq];
    {
        float4 o;
        o.x = acc[0][0] + cbv.x; o.y = acc[0][1] + cbv.y;
        o.z = acc[0][2] + cbv.z; o.w = acc[0][3] + cbv.w;
        *(float4*)&ob[(size_t)gs * ND + jq * 4] = o;
        o.x = acc[1][0] + cbv.x; o.y = acc[1][1] + cbv.y;
        o.z = acc[1][2] + cbv.z; o.w = acc[1][3] + cbv.w;
        *(float4*)&ob[(size_t)(gs + 8) * ND + jq * 4] = o;
    }
}

extern "C" void kernel_launch(void* const* d_in, const int* in_sizes, int n_in,
                              void* d_out, int out_size, void* d_ws, size_t ws_size,
                              hipStream_t stream) {
    const float* emb    = (const float*)d_in[0];   // [B,A,D]
    const float* coords = (const float*)d_in[1];   // [B,A,2]
    const int*   mask   = (const int*)d_in[2];     // [B,A]
    const float* W1     = (const float*)d_in[3];   // [D,D]
    const float* b1     = (const float*)d_in[4];   // [D]
    const float* W2     = (const float*)d_in[5];   // [D,D]
    const float* b2     = (const float*)d_in[6];   // [D]

    float* out0 = (float*)d_out;                    // [B,A,D]
    float* out1 = out0 + (size_t)NB * NA * ND;      // group_mask
    float* out2 = out1 + (size_t)NB * NA;           // agent_to_group

    // workspace: tokens, gcount, empty_row
    float* ws_tok   = (float*)d_ws;                       // B*A*D
    int*   ws_gcnt  = (int*)(ws_tok + (size_t)NB * NA * ND); // B
    float* ws_empty = (float*)(ws_gcnt + NB);             // D

    fused_kernel<<<NB + 1, 1024, 0, stream>>>(
        (const float2*)coords, mask, emb,
        ws_gcnt, ws_tok, out1, out2,
        b1, W2, b2, ws_empty);
    mlp_kernel<<<dim3(NA / TG, NB), 256, 0, stream>>>(
        ws_tok, ws_gcnt, ws_empty,
        (const float4*)W1, b1, (const float4*)W2, b2, out0);
}